// Round 17
// baseline (3157.760 us; speedup 1.0000x reference)
//
#include <hip/hip_runtime.h>
#include <hip/hip_bf16.h>

// ---------------------------------------------------------------------------
// CRQ-VAE forward: encoder MLP (768->512->256->64, relu,relu,none) + 4-level
// residual VQ (K=256, e=64) with loss and codes.
// Outputs (flat): x_q [N*64] f32, rq_loss [1] f32, codes [4*N] f32.
// R17: gemm128 moves to BK=32 (half the barriers per K; k-order per output
// element still ascending -> z bitwise identical). rvq_w1 (single-wave, R16)
// and gemm_bias unchanged.
// ---------------------------------------------------------------------------

typedef double d2v __attribute__((ext_vector_type(2)));

// ======================= 128x128 fp32 GEMM (N%128==0, K%32==0) =============
template<bool RELU, int NCOLSHIFT>
__global__ __launch_bounds__(256) void gemm128(
    const float* __restrict__ A, const float* __restrict__ W,
    const float* __restrict__ bias, float* __restrict__ C,
    int M, int N, int K)
{
    __shared__ float As[32][132];   // [k][m]  (A transposed in LDS)
    __shared__ float Bs[32][132];   // [k][n]

    const int nwg  = gridDim.x * gridDim.y;
    const int id   = blockIdx.y * gridDim.x + blockIdx.x;
    const int xcd  = id & 7;
    const int rest = id >> 3;
    const int q8   = nwg >> 3, r8 = nwg & 7;
    const int wg   = (xcd < r8 ? xcd * (q8 + 1) : r8 * (q8 + 1) + (xcd - r8) * q8) + rest;
    const int NCOL = 1 << NCOLSHIFT;

    const int col0 = (wg & (NCOL - 1)) * 128;
    const int row0 = (wg >> NCOLSHIFT) * 128;

    const int tid = threadIdx.x;
    const int tx = tid & 15;        // col group
    const int ty = tid >> 4;        // row group

    const float* Ab = A + (size_t)row0 * K;
    const float* Wb = W + col0;

    // staging positions: A-tile 128x32 = 1024 float4 (4/thread),
    //                    B-tile 32x128 = 1024 float4 (4/thread)
    int amv[4], akv[4], bkv[4], bnv[4];
#pragma unroll
    for (int i = 0; i < 4; ++i) {
        int p = tid + i * 256;
        amv[i] = p >> 3;  akv[i] = (p & 7) * 4;
        bkv[i] = p >> 5;  bnv[i] = (p & 31) * 4;
    }

    float acc[8][8] = {};
    float4 sa[4], sb[4];

    // ---- preload tile 0 ----
#pragma unroll
    for (int i = 0; i < 4; ++i) {
        sa[i] = *reinterpret_cast<const float4*>(Ab + (size_t)amv[i] * K + akv[i]);
        sb[i] = *reinterpret_cast<const float4*>(Wb + (size_t)bkv[i] * N + bnv[i]);
    }
#pragma unroll
    for (int i = 0; i < 4; ++i) {
        As[akv[i] + 0][amv[i]] = sa[i].x;
        As[akv[i] + 1][amv[i]] = sa[i].y;
        As[akv[i] + 2][amv[i]] = sa[i].z;
        As[akv[i] + 3][amv[i]] = sa[i].w;
        *reinterpret_cast<float4*>(&Bs[bkv[i]][bnv[i]]) = sb[i];
    }
    __syncthreads();

    for (int k0 = 0; k0 < K; k0 += 32) {
        const bool hasNext = (k0 + 32 < K);
        if (hasNext) {
            const float* An = Ab + k0 + 32;
            const float* Wn = Wb + (size_t)(k0 + 32) * N;
#pragma unroll
            for (int i = 0; i < 4; ++i) {
                sa[i] = *reinterpret_cast<const float4*>(An + (size_t)amv[i] * K + akv[i]);
                sb[i] = *reinterpret_cast<const float4*>(Wn + (size_t)bkv[i] * N + bnv[i]);
            }
        }

#pragma unroll
        for (int kk = 0; kk < 32; ++kk) {
            float4 a0 = *reinterpret_cast<const float4*>(&As[kk][ty * 4]);
            float4 a1 = *reinterpret_cast<const float4*>(&As[kk][64 + ty * 4]);
            float4 b0 = *reinterpret_cast<const float4*>(&Bs[kk][tx * 4]);
            float4 b1 = *reinterpret_cast<const float4*>(&Bs[kk][64 + tx * 4]);
            float ar[8] = {a0.x, a0.y, a0.z, a0.w, a1.x, a1.y, a1.z, a1.w};
            float br[8] = {b0.x, b0.y, b0.z, b0.w, b1.x, b1.y, b1.z, b1.w};
#pragma unroll
            for (int m = 0; m < 8; ++m)
#pragma unroll
                for (int n = 0; n < 8; ++n)
                    acc[m][n] = fmaf(ar[m], br[n], acc[m][n]);
        }

        if (hasNext) {
            __syncthreads();
#pragma unroll
            for (int i = 0; i < 4; ++i) {
                As[akv[i] + 0][amv[i]] = sa[i].x;
                As[akv[i] + 1][amv[i]] = sa[i].y;
                As[akv[i] + 2][amv[i]] = sa[i].z;
                As[akv[i] + 3][amv[i]] = sa[i].w;
                *reinterpret_cast<float4*>(&Bs[bkv[i]][bnv[i]]) = sb[i];
            }
            __syncthreads();
        }
    }

    // ---- epilogue ----
    float bl[4], bh[4];
#pragma unroll
    for (int n = 0; n < 4; ++n) {
        bl[n] = bias[col0 + tx * 4 + n];
        bh[n] = bias[col0 + 64 + tx * 4 + n];
    }
#pragma unroll
    for (int half = 0; half < 2; ++half) {
#pragma unroll
        for (int r = 0; r < 4; ++r) {
            int m = half * 4 + r;
            int row = row0 + half * 64 + ty * 4 + r;
            float4 lo, hi;
            lo.x = acc[m][0] + bl[0]; lo.y = acc[m][1] + bl[1];
            lo.z = acc[m][2] + bl[2]; lo.w = acc[m][3] + bl[3];
            hi.x = acc[m][4] + bh[0]; hi.y = acc[m][5] + bh[1];
            hi.z = acc[m][6] + bh[2]; hi.w = acc[m][7] + bh[3];
            if (RELU) {
                lo.x = fmaxf(lo.x, 0.f); lo.y = fmaxf(lo.y, 0.f);
                lo.z = fmaxf(lo.z, 0.f); lo.w = fmaxf(lo.w, 0.f);
                hi.x = fmaxf(hi.x, 0.f); hi.y = fmaxf(hi.y, 0.f);
                hi.z = fmaxf(hi.z, 0.f); hi.w = fmaxf(hi.w, 0.f);
            }
            float* Cr = C + (size_t)row * N + col0;
            *reinterpret_cast<float4*>(Cr + tx * 4) = lo;
            *reinterpret_cast<float4*>(Cr + 64 + tx * 4) = hi;
        }
    }
}

// ================== 128x64 fp32 GEMM (GEMM3, N==64) ========================
template<bool RELU>
__global__ __launch_bounds__(256) void gemm_bias(
    const float* __restrict__ A, const float* __restrict__ W,
    const float* __restrict__ bias, float* __restrict__ C,
    int M, int N, int K)
{
    __shared__ float As[16][132];
    __shared__ float Bs[16][68];

    const int tid = threadIdx.x;
    const int tx = tid & 15;
    const int ty = tid >> 4;
    const int col0 = blockIdx.x * 64;
    const int row0 = blockIdx.y * 128;

    const float* Ab = A + (size_t)row0 * K;
    const float* Wb = W + col0;

    float acc[8][4] = {};

    for (int k0 = 0; k0 < K; k0 += 16) {
#pragma unroll
        for (int i = 0; i < 2; ++i) {
            int pos = tid + i * 256;
            int m  = pos >> 2;
            int k4 = (pos & 3) * 4;
            float4 v = *reinterpret_cast<const float4*>(Ab + (size_t)m * K + k0 + k4);
            As[k4 + 0][m] = v.x; As[k4 + 1][m] = v.y;
            As[k4 + 2][m] = v.z; As[k4 + 3][m] = v.w;
        }
        {
            int kk = tid >> 4;
            int n4 = (tid & 15) * 4;
            float4 v = *reinterpret_cast<const float4*>(Wb + (size_t)(k0 + kk) * N + n4);
            *reinterpret_cast<float4*>(&Bs[kk][n4]) = v;
        }
        __syncthreads();
#pragma unroll
        for (int kk = 0; kk < 16; ++kk) {
            float4 a0 = *reinterpret_cast<const float4*>(&As[kk][ty * 8]);
            float4 a1 = *reinterpret_cast<const float4*>(&As[kk][ty * 8 + 4]);
            float4 bv = *reinterpret_cast<const float4*>(&Bs[kk][tx * 4]);
            float a[8] = {a0.x, a0.y, a0.z, a0.w, a1.x, a1.y, a1.z, a1.w};
            float b[4] = {bv.x, bv.y, bv.z, bv.w};
#pragma unroll
            for (int m = 0; m < 8; ++m)
#pragma unroll
                for (int n = 0; n < 4; ++n)
                    acc[m][n] = fmaf(a[m], b[n], acc[m][n]);
        }
        __syncthreads();
    }

    float bv[4];
#pragma unroll
    for (int n = 0; n < 4; ++n) bv[n] = bias[col0 + tx * 4 + n];
#pragma unroll
    for (int m = 0; m < 8; ++m) {
        int row = row0 + ty * 8 + m;
        float4 o;
        float v0 = acc[m][0] + bv[0];
        float v1 = acc[m][1] + bv[1];
        float v2 = acc[m][2] + bv[2];
        float v3 = acc[m][3] + bv[3];
        if (RELU) {
            v0 = fmaxf(v0, 0.f); v1 = fmaxf(v1, 0.f);
            v2 = fmaxf(v2, 0.f); v3 = fmaxf(v3, 0.f);
        }
        o.x = v0; o.y = v1; o.z = v2; o.w = v3;
        *reinterpret_cast<float4*>(C + (size_t)row * N + col0 + tx * 4) = o;
    }
}

// ---------------------------------------------------------------------------
// codebook norms: cn64[c] (fp64) and cnf[c] (f32 rounding of cn64)
__global__ void cb_norms(const float* __restrict__ cb,
                         double* __restrict__ cn64, float* __restrict__ cnf) {
    int c = blockIdx.x * 64 + threadIdx.x;   // 16 blocks x 64
    const float* p = cb + (size_t)c * 64;
    double s = 0.0;
#pragma unroll
    for (int j = 0; j < 64; ++j) {
        double v = (double)p[j];
        s = fma(v, v, s);
    }
    cn64[c] = s;
    cnf[c]  = (float)s;
}

// widened codebook: cbw[i] = -2 * cb[i]  (same flat [4,256,64] layout, fp64)
__global__ void build_cbw(const float* __restrict__ cb, double* __restrict__ cbw) {
    int i = blockIdx.x * 256 + threadIdx.x;   // 256 blocks -> 65536
    cbw[i] = -2.0 * (double)cb[i];
}

// ---------------------------------------------------------------------------
#define EGUARD 1e-3   // >= 2.5x worst-case f32 scan error bound

// exact fp64 rank: R0 + sum_j p[j]*rd[j]; FULL unroll -> static rd indexing
__device__ __forceinline__ double rank64(const double* __restrict__ p,
                                         double R0, const float (&rd)[64]) {
    double c0 = 0.0, c1 = 0.0, c2 = 0.0, c3 = 0.0;
#pragma unroll
    for (int j = 0; j < 16; ++j) {
        d2v x = *reinterpret_cast<const d2v*>(p + j * 4);
        d2v y = *reinterpret_cast<const d2v*>(p + j * 4 + 2);
        c0 = fma(x[0], (double)rd[j * 4 + 0], c0);
        c1 = fma(x[1], (double)rd[j * 4 + 1], c1);
        c2 = fma(y[0], (double)rd[j * 4 + 2], c2);
        c3 = fma(y[1], (double)rd[j * 4 + 3], c3);
    }
    return R0 + ((c0 + c1) + (c2 + c3));
}

// RVQ w1 (R16 verbatim): one wave per 64 rows; scans all 256 codes.
__global__ __launch_bounds__(64) void rvq_w1(
    const float* __restrict__ z,       // [N, 64]
    const float* __restrict__ cbf,     // [4,256,64] f32 codebook
    const double* __restrict__ cbw,    // [4,256,64] f64 (-2*cb)
    const double* __restrict__ cn64,   // [1024] f64 code norms
    const float* __restrict__ cnf,     // [1024] f32 code norms
    float* __restrict__ xq,            // d_out base [N,64]
    float* __restrict__ codes,         // d_out codes base [4,N]
    double* __restrict__ partials,     // [N/64]
    int row0, int Ntot)
{
    const int lane = threadIdx.x;      // 0..63 (one wave)
    const int blk  = blockIdx.x;
    const int grow0 = row0 + blk * 64;

    float rd[64];
    const float* zr = z + (size_t)(blk * 64 + lane) * 64;
#pragma unroll
    for (int q = 0; q < 16; ++q) {
        float4 v = *reinterpret_cast<const float4*>(zr + q * 4);
        rd[q * 4 + 0] = v.x; rd[q * 4 + 1] = v.y;
        rd[q * 4 + 2] = v.z; rd[q * 4 + 3] = v.w;
    }

    double sse = 0.0;

    for (int lv = 0; lv < 4; ++lv) {
        const int cbase = lv * 256;
        const float* cwl = cbf + (size_t)cbase * 64;
        const float* cnl = cnf + cbase;

        float d1 = 3.4e38f, d2 = 3.4e38f;
        int   i1 = 0,       i2 = 0;

#pragma unroll 2
        for (int c = 0; c < 256; ++c) {
            const float* cp = cwl + c * 64;
            float acc8[8];
#pragma unroll
            for (int q = 0; q < 8; ++q) {
                float4 va = *reinterpret_cast<const float4*>(cp + q * 8);
                float4 vb = *reinterpret_cast<const float4*>(cp + q * 8 + 4);
                float t = 0.f;
                t = fmaf(va.x, rd[q * 8 + 0], t);
                t = fmaf(va.y, rd[q * 8 + 1], t);
                t = fmaf(va.z, rd[q * 8 + 2], t);
                t = fmaf(va.w, rd[q * 8 + 3], t);
                t = fmaf(vb.x, rd[q * 8 + 4], t);
                t = fmaf(vb.y, rd[q * 8 + 5], t);
                t = fmaf(vb.z, rd[q * 8 + 6], t);
                t = fmaf(vb.w, rd[q * 8 + 7], t);
                acc8[q] = t;
            }
            float dot = ((acc8[0] + acc8[1]) + (acc8[2] + acc8[3]))
                      + ((acc8[4] + acc8[5]) + (acc8[6] + acc8[7]));
            float d = fmaf(-2.f, dot, cnl[c]);
            if (d < d1) { d2 = d1; i2 = i1; d1 = d; i1 = c; }
            else if (d < d2) { d2 = d; i2 = c; }
        }

        // exact fp64 verify of scan top-2; accept iff provably global min
        double R1 = rank64(cbw + (size_t)(cbase + i1) * 64, cn64[cbase + i1], rd);
        double R2 = rank64(cbw + (size_t)(cbase + i2) * 64, cn64[cbase + i2], rd);
        int ci; double Rw;
        if (R1 < R2)      { ci = i1; Rw = R1; }
        else if (R2 < R1) { ci = i2; Rw = R2; }
        else              { ci = (i1 < i2) ? i1 : i2; Rw = R1; }

        if (!(Rw < (double)d2 - EGUARD)) {
            // full exact rescan (first-min => lowest index); rare
            double dmin = 1.0e300; int imin = 0;
#pragma unroll 1
            for (int c = 0; c < 256; ++c) {
                double R = rank64(cbw + (size_t)(cbase + c) * 64,
                                  cn64[cbase + c], rd);
                if (R < dmin) { dmin = R; imin = c; }
            }
            ci = imin;
        }

        // gather q, accumulate loss (fp64), f32 residual update (matches ref)
        const float* qp = cbf + (size_t)(cbase + ci) * 64;
        double lsse = 0.0;
#pragma unroll
        for (int q = 0; q < 16; ++q) {
            float4 qv = *reinterpret_cast<const float4*>(qp + q * 4);
            float r0 = rd[q * 4 + 0], r1 = rd[q * 4 + 1];
            float r2 = rd[q * 4 + 2], r3 = rd[q * 4 + 3];
            float e0 = qv.x - r0, e1 = qv.y - r1;
            float e2 = qv.z - r2, e3 = qv.w - r3;
            lsse = fma((double)e0, (double)e0, lsse);
            lsse = fma((double)e1, (double)e1, lsse);
            lsse = fma((double)e2, (double)e2, lsse);
            lsse = fma((double)e3, (double)e3, lsse);
            rd[q * 4 + 0] = r0 - qv.x; rd[q * 4 + 1] = r1 - qv.y;
            rd[q * 4 + 2] = r2 - qv.z; rd[q * 4 + 3] = r3 - qv.w;
        }
        sse += lsse;
        codes[(size_t)lv * Ntot + grow0 + lane] = (float)ci;
    }

    // ---- x_q = z - r_final ; per-block loss partial ----
    {
        size_t base = (size_t)(grow0 + lane) * 64;
#pragma unroll
        for (int q = 0; q < 16; ++q) {
            float4 zv = *reinterpret_cast<const float4*>(zr + q * 4);
            float4 o;
            o.x = zv.x - rd[q * 4 + 0];
            o.y = zv.y - rd[q * 4 + 1];
            o.z = zv.z - rd[q * 4 + 2];
            o.w = zv.w - rd[q * 4 + 3];
            *reinterpret_cast<float4*>(xq + base + q * 4) = o;
        }
        double s = sse;
#pragma unroll
        for (int off = 32; off > 0; off >>= 1) {
            union { double d; int i[2]; } u; u.d = s;
            u.i[0] = __shfl_down(u.i[0], off, 64);
            u.i[1] = __shfl_down(u.i[1], off, 64);
            s += u.d;
        }
        if (lane == 0) partials[grow0 >> 6] = s;
    }
}

// ---------------------------------------------------------------------------
__global__ void loss_final(const double* __restrict__ partials, int n,
                           float* __restrict__ out, double scale) {
    __shared__ double s[256];
    double acc = 0.0;
    for (int i = threadIdx.x; i < n; i += 256) acc += partials[i];
    s[threadIdx.x] = acc;
    __syncthreads();
    for (int off = 128; off > 0; off >>= 1) {
        if ((int)threadIdx.x < off) s[threadIdx.x] += s[threadIdx.x + off];
        __syncthreads();
    }
    if (threadIdx.x == 0) *out = (float)(s[0] * scale);
}

// ---------------------------------------------------------------------------
extern "C" void kernel_launch(void* const* d_in, const int* in_sizes, int n_in,
                              void* d_out, int out_size, void* d_ws, size_t ws_size,
                              hipStream_t stream) {
    const float* x  = (const float*)d_in[0];
    const float* W0 = (const float*)d_in[1];
    const float* b0 = (const float*)d_in[2];
    const float* W1 = (const float*)d_in[3];
    const float* b1 = (const float*)d_in[4];
    const float* W2 = (const float*)d_in[5];
    const float* b2 = (const float*)d_in[6];
    const float* cb = (const float*)d_in[7];

    const int N = in_sizes[0] / 768;

    float* out   = (float*)d_out;
    float* xq    = out;                      // [N*64]
    float* loss  = out + (size_t)N * 64;     // [1]
    float* codes = loss + 1;                 // [4*N]

    const int nblk_total = N / 64;
    const size_t tail_floats = 131072 + 2048 + 2 * (size_t)nblk_total + 1024 + 64;

    size_t avail = ws_size / 4;
    avail = (avail > tail_floats) ? (avail - tail_floats) : 0;
    int Nc = (int)(avail / 832);
    Nc = (Nc / 128) * 128;
    if (Nc > N) Nc = N;
    if (Nc < 128) Nc = 128;

    float* ws = (float*)d_ws;
    float* h0 = ws;
    float* h1 = h0 + (size_t)Nc * 512;
    float* z  = h1 + (size_t)Nc * 256;
    double* cbw      = (double*)(ws + (size_t)Nc * 832);  // 16B-aligned (Nc%128==0)
    double* cn64     = cbw + 65536;
    double* partials = cn64 + 1024;
    float*  cnf      = (float*)(partials + nblk_total);

    cb_norms <<<16, 64, 0, stream>>>(cb, cn64, cnf);
    build_cbw<<<256, 256, 0, stream>>>(cb, cbw);

    for (int r0 = 0; r0 < N; r0 += Nc) {
        int cur = (N - r0 < Nc) ? (N - r0) : Nc;
        gemm128<true, 2><<<dim3(512 / 128, cur / 128), 256, 0, stream>>>(
            x + (size_t)r0 * 768, W0, b0, h0, cur, 512, 768);
        gemm128<true, 1><<<dim3(256 / 128, cur / 128), 256, 0, stream>>>(
            h0, W1, b1, h1, cur, 256, 512);
        gemm_bias<false><<<dim3(1, cur / 128), 256, 0, stream>>>(
            h1, W2, b2, z, cur, 64, 256);
        rvq_w1<<<cur / 64, 64, 0, stream>>>(
            z, cb, cbw, cn64, cnf, xq, codes, partials, r0, N);
    }

    loss_final<<<1, 256, 0, stream>>>(partials, nblk_total, loss,
                                      1.25 / (4.0 * (double)N * 64.0));
}

// Round 18
// 2493.354 us; speedup vs baseline: 1.2665x; 1.2665x over previous
//
#include <hip/hip_runtime.h>
#include <hip/hip_bf16.h>

// ---------------------------------------------------------------------------
// CRQ-VAE forward: encoder MLP (768->512->256->64, relu,relu,none) + 4-level
// residual VQ (K=256, e=64) with loss and codes.
// Outputs (flat): x_q [N*64] f32, rq_loss [1] f32, codes [4*N] f32.
// R18: revert to R16 (best measured, 2503us): BK=16 2-barrier swizzled
// gemm128 (~8 blocks/CU) + single-wave rvq_w1. R17's BK=32 halved occupancy
// (33.8KB LDS -> 4 blocks/CU) and tripled bank conflicts: 1220->1910us.
// ---------------------------------------------------------------------------

typedef double d2v __attribute__((ext_vector_type(2)));

// ======================= 128x128 fp32 GEMM (N%128==0) ======================
template<bool RELU, int NCOLSHIFT>
__global__ __launch_bounds__(256) void gemm128(
    const float* __restrict__ A, const float* __restrict__ W,
    const float* __restrict__ bias, float* __restrict__ C,
    int M, int N, int K)
{
    __shared__ float As[16][132];   // [k][m]  (A transposed in LDS)
    __shared__ float Bs[16][132];   // [k][n]

    const int nwg  = gridDim.x * gridDim.y;
    const int id   = blockIdx.y * gridDim.x + blockIdx.x;
    const int xcd  = id & 7;
    const int rest = id >> 3;
    const int q8   = nwg >> 3, r8 = nwg & 7;
    const int wg   = (xcd < r8 ? xcd * (q8 + 1) : r8 * (q8 + 1) + (xcd - r8) * q8) + rest;
    const int NCOL = 1 << NCOLSHIFT;

    const int col0 = (wg & (NCOL - 1)) * 128;
    const int row0 = (wg >> NCOLSHIFT) * 128;

    const int tid = threadIdx.x;
    const int tx = tid & 15;        // col group
    const int ty = tid >> 4;        // row group

    const float* Ab = A + (size_t)row0 * K;
    const float* Wb = W + col0;

    const int am0 = tid >> 2,          ak0 = (tid & 3) * 4;
    const int am1 = (tid + 256) >> 2,  ak1 = ((tid + 256) & 3) * 4;
    const int bk0 = tid >> 5,          bn0 = (tid & 31) * 4;
    const int bk1 = (tid + 256) >> 5,  bn1 = ((tid + 256) & 31) * 4;

    float acc[8][8] = {};

    // ---- preload tile 0 ----
    float4 sa0 = *reinterpret_cast<const float4*>(Ab + (size_t)am0 * K + ak0);
    float4 sa1 = *reinterpret_cast<const float4*>(Ab + (size_t)am1 * K + ak1);
    float4 sb0 = *reinterpret_cast<const float4*>(Wb + (size_t)bk0 * N + bn0);
    float4 sb1 = *reinterpret_cast<const float4*>(Wb + (size_t)bk1 * N + bn1);
    As[ak0 + 0][am0] = sa0.x; As[ak0 + 1][am0] = sa0.y;
    As[ak0 + 2][am0] = sa0.z; As[ak0 + 3][am0] = sa0.w;
    As[ak1 + 0][am1] = sa1.x; As[ak1 + 1][am1] = sa1.y;
    As[ak1 + 2][am1] = sa1.z; As[ak1 + 3][am1] = sa1.w;
    *reinterpret_cast<float4*>(&Bs[bk0][bn0]) = sb0;
    *reinterpret_cast<float4*>(&Bs[bk1][bn1]) = sb1;
    __syncthreads();

    for (int k0 = 0; k0 < K; k0 += 16) {
        const bool hasNext = (k0 + 16 < K);
        if (hasNext) {
            const float* An = Ab + k0 + 16;
            const float* Wn = Wb + (size_t)(k0 + 16) * N;
            sa0 = *reinterpret_cast<const float4*>(An + (size_t)am0 * K + ak0);
            sa1 = *reinterpret_cast<const float4*>(An + (size_t)am1 * K + ak1);
            sb0 = *reinterpret_cast<const float4*>(Wn + (size_t)bk0 * N + bn0);
            sb1 = *reinterpret_cast<const float4*>(Wn + (size_t)bk1 * N + bn1);
        }

#pragma unroll
        for (int kk = 0; kk < 16; ++kk) {
            float4 a0 = *reinterpret_cast<const float4*>(&As[kk][ty * 4]);
            float4 a1 = *reinterpret_cast<const float4*>(&As[kk][64 + ty * 4]);
            float4 b0 = *reinterpret_cast<const float4*>(&Bs[kk][tx * 4]);
            float4 b1 = *reinterpret_cast<const float4*>(&Bs[kk][64 + tx * 4]);
            float ar[8] = {a0.x, a0.y, a0.z, a0.w, a1.x, a1.y, a1.z, a1.w};
            float br[8] = {b0.x, b0.y, b0.z, b0.w, b1.x, b1.y, b1.z, b1.w};
#pragma unroll
            for (int m = 0; m < 8; ++m)
#pragma unroll
                for (int n = 0; n < 8; ++n)
                    acc[m][n] = fmaf(ar[m], br[n], acc[m][n]);
        }

        if (hasNext) {
            __syncthreads();
            As[ak0 + 0][am0] = sa0.x; As[ak0 + 1][am0] = sa0.y;
            As[ak0 + 2][am0] = sa0.z; As[ak0 + 3][am0] = sa0.w;
            As[ak1 + 0][am1] = sa1.x; As[ak1 + 1][am1] = sa1.y;
            As[ak1 + 2][am1] = sa1.z; As[ak1 + 3][am1] = sa1.w;
            *reinterpret_cast<float4*>(&Bs[bk0][bn0]) = sb0;
            *reinterpret_cast<float4*>(&Bs[bk1][bn1]) = sb1;
            __syncthreads();
        }
    }

    // ---- epilogue ----
    float bl[4], bh[4];
#pragma unroll
    for (int n = 0; n < 4; ++n) {
        bl[n] = bias[col0 + tx * 4 + n];
        bh[n] = bias[col0 + 64 + tx * 4 + n];
    }
#pragma unroll
    for (int half = 0; half < 2; ++half) {
#pragma unroll
        for (int r = 0; r < 4; ++r) {
            int m = half * 4 + r;
            int row = row0 + half * 64 + ty * 4 + r;
            float4 lo, hi;
            lo.x = acc[m][0] + bl[0]; lo.y = acc[m][1] + bl[1];
            lo.z = acc[m][2] + bl[2]; lo.w = acc[m][3] + bl[3];
            hi.x = acc[m][4] + bh[0]; hi.y = acc[m][5] + bh[1];
            hi.z = acc[m][6] + bh[2]; hi.w = acc[m][7] + bh[3];
            if (RELU) {
                lo.x = fmaxf(lo.x, 0.f); lo.y = fmaxf(lo.y, 0.f);
                lo.z = fmaxf(lo.z, 0.f); lo.w = fmaxf(lo.w, 0.f);
                hi.x = fmaxf(hi.x, 0.f); hi.y = fmaxf(hi.y, 0.f);
                hi.z = fmaxf(hi.z, 0.f); hi.w = fmaxf(hi.w, 0.f);
            }
            float* Cr = C + (size_t)row * N + col0;
            *reinterpret_cast<float4*>(Cr + tx * 4) = lo;
            *reinterpret_cast<float4*>(Cr + 64 + tx * 4) = hi;
        }
    }
}

// ================== 128x64 fp32 GEMM (GEMM3, N==64) ========================
template<bool RELU>
__global__ __launch_bounds__(256) void gemm_bias(
    const float* __restrict__ A, const float* __restrict__ W,
    const float* __restrict__ bias, float* __restrict__ C,
    int M, int N, int K)
{
    __shared__ float As[16][132];
    __shared__ float Bs[16][68];

    const int tid = threadIdx.x;
    const int tx = tid & 15;
    const int ty = tid >> 4;
    const int col0 = blockIdx.x * 64;
    const int row0 = blockIdx.y * 128;

    const float* Ab = A + (size_t)row0 * K;
    const float* Wb = W + col0;

    float acc[8][4] = {};

    for (int k0 = 0; k0 < K; k0 += 16) {
#pragma unroll
        for (int i = 0; i < 2; ++i) {
            int pos = tid + i * 256;
            int m  = pos >> 2;
            int k4 = (pos & 3) * 4;
            float4 v = *reinterpret_cast<const float4*>(Ab + (size_t)m * K + k0 + k4);
            As[k4 + 0][m] = v.x; As[k4 + 1][m] = v.y;
            As[k4 + 2][m] = v.z; As[k4 + 3][m] = v.w;
        }
        {
            int kk = tid >> 4;
            int n4 = (tid & 15) * 4;
            float4 v = *reinterpret_cast<const float4*>(Wb + (size_t)(k0 + kk) * N + n4);
            *reinterpret_cast<float4*>(&Bs[kk][n4]) = v;
        }
        __syncthreads();
#pragma unroll
        for (int kk = 0; kk < 16; ++kk) {
            float4 a0 = *reinterpret_cast<const float4*>(&As[kk][ty * 8]);
            float4 a1 = *reinterpret_cast<const float4*>(&As[kk][ty * 8 + 4]);
            float4 bv = *reinterpret_cast<const float4*>(&Bs[kk][tx * 4]);
            float a[8] = {a0.x, a0.y, a0.z, a0.w, a1.x, a1.y, a1.z, a1.w};
            float b[4] = {bv.x, bv.y, bv.z, bv.w};
#pragma unroll
            for (int m = 0; m < 8; ++m)
#pragma unroll
                for (int n = 0; n < 4; ++n)
                    acc[m][n] = fmaf(a[m], b[n], acc[m][n]);
        }
        __syncthreads();
    }

    float bv[4];
#pragma unroll
    for (int n = 0; n < 4; ++n) bv[n] = bias[col0 + tx * 4 + n];
#pragma unroll
    for (int m = 0; m < 8; ++m) {
        int row = row0 + ty * 8 + m;
        float4 o;
        float v0 = acc[m][0] + bv[0];
        float v1 = acc[m][1] + bv[1];
        float v2 = acc[m][2] + bv[2];
        float v3 = acc[m][3] + bv[3];
        if (RELU) {
            v0 = fmaxf(v0, 0.f); v1 = fmaxf(v1, 0.f);
            v2 = fmaxf(v2, 0.f); v3 = fmaxf(v3, 0.f);
        }
        o.x = v0; o.y = v1; o.z = v2; o.w = v3;
        *reinterpret_cast<float4*>(C + (size_t)row * N + col0 + tx * 4) = o;
    }
}

// ---------------------------------------------------------------------------
// codebook norms: cn64[c] (fp64) and cnf[c] (f32 rounding of cn64)
__global__ void cb_norms(const float* __restrict__ cb,
                         double* __restrict__ cn64, float* __restrict__ cnf) {
    int c = blockIdx.x * 64 + threadIdx.x;   // 16 blocks x 64
    const float* p = cb + (size_t)c * 64;
    double s = 0.0;
#pragma unroll
    for (int j = 0; j < 64; ++j) {
        double v = (double)p[j];
        s = fma(v, v, s);
    }
    cn64[c] = s;
    cnf[c]  = (float)s;
}

// widened codebook: cbw[i] = -2 * cb[i]  (same flat [4,256,64] layout, fp64)
__global__ void build_cbw(const float* __restrict__ cb, double* __restrict__ cbw) {
    int i = blockIdx.x * 256 + threadIdx.x;   // 256 blocks -> 65536
    cbw[i] = -2.0 * (double)cb[i];
}

// ---------------------------------------------------------------------------
#define EGUARD 1e-3   // >= 2.5x worst-case f32 scan error bound

// exact fp64 rank: R0 + sum_j p[j]*rd[j]; FULL unroll -> static rd indexing
__device__ __forceinline__ double rank64(const double* __restrict__ p,
                                         double R0, const float (&rd)[64]) {
    double c0 = 0.0, c1 = 0.0, c2 = 0.0, c3 = 0.0;
#pragma unroll
    for (int j = 0; j < 16; ++j) {
        d2v x = *reinterpret_cast<const d2v*>(p + j * 4);
        d2v y = *reinterpret_cast<const d2v*>(p + j * 4 + 2);
        c0 = fma(x[0], (double)rd[j * 4 + 0], c0);
        c1 = fma(x[1], (double)rd[j * 4 + 1], c1);
        c2 = fma(y[0], (double)rd[j * 4 + 2], c2);
        c3 = fma(y[1], (double)rd[j * 4 + 3], c3);
    }
    return R0 + ((c0 + c1) + (c2 + c3));
}

// RVQ w1: one wave per 64 rows; scans all 256 codes. No LDS, no barriers.
// Scan distances bitwise identical to v5; selection = exact fp64 argmin
// (top-2 verify, guard, full-rescan fallback), lowest-index ties.
__global__ __launch_bounds__(64) void rvq_w1(
    const float* __restrict__ z,       // [N, 64]
    const float* __restrict__ cbf,     // [4,256,64] f32 codebook
    const double* __restrict__ cbw,    // [4,256,64] f64 (-2*cb)
    const double* __restrict__ cn64,   // [1024] f64 code norms
    const float* __restrict__ cnf,     // [1024] f32 code norms
    float* __restrict__ xq,            // d_out base [N,64]
    float* __restrict__ codes,         // d_out codes base [4,N]
    double* __restrict__ partials,     // [N/64]
    int row0, int Ntot)
{
    const int lane = threadIdx.x;      // 0..63 (one wave)
    const int blk  = blockIdx.x;
    const int grow0 = row0 + blk * 64;

    float rd[64];
    const float* zr = z + (size_t)(blk * 64 + lane) * 64;
#pragma unroll
    for (int q = 0; q < 16; ++q) {
        float4 v = *reinterpret_cast<const float4*>(zr + q * 4);
        rd[q * 4 + 0] = v.x; rd[q * 4 + 1] = v.y;
        rd[q * 4 + 2] = v.z; rd[q * 4 + 3] = v.w;
    }

    double sse = 0.0;

    for (int lv = 0; lv < 4; ++lv) {
        const int cbase = lv * 256;
        const float* cwl = cbf + (size_t)cbase * 64;
        const float* cnl = cnf + cbase;

        float d1 = 3.4e38f, d2 = 3.4e38f;
        int   i1 = 0,       i2 = 0;

#pragma unroll 2
        for (int c = 0; c < 256; ++c) {
            const float* cp = cwl + c * 64;
            float acc8[8];
#pragma unroll
            for (int q = 0; q < 8; ++q) {
                float4 va = *reinterpret_cast<const float4*>(cp + q * 8);
                float4 vb = *reinterpret_cast<const float4*>(cp + q * 8 + 4);
                float t = 0.f;
                t = fmaf(va.x, rd[q * 8 + 0], t);
                t = fmaf(va.y, rd[q * 8 + 1], t);
                t = fmaf(va.z, rd[q * 8 + 2], t);
                t = fmaf(va.w, rd[q * 8 + 3], t);
                t = fmaf(vb.x, rd[q * 8 + 4], t);
                t = fmaf(vb.y, rd[q * 8 + 5], t);
                t = fmaf(vb.z, rd[q * 8 + 6], t);
                t = fmaf(vb.w, rd[q * 8 + 7], t);
                acc8[q] = t;
            }
            float dot = ((acc8[0] + acc8[1]) + (acc8[2] + acc8[3]))
                      + ((acc8[4] + acc8[5]) + (acc8[6] + acc8[7]));
            float d = fmaf(-2.f, dot, cnl[c]);
            if (d < d1) { d2 = d1; i2 = i1; d1 = d; i1 = c; }
            else if (d < d2) { d2 = d; i2 = c; }
        }

        // exact fp64 verify of scan top-2; accept iff provably global min
        double R1 = rank64(cbw + (size_t)(cbase + i1) * 64, cn64[cbase + i1], rd);
        double R2 = rank64(cbw + (size_t)(cbase + i2) * 64, cn64[cbase + i2], rd);
        int ci; double Rw;
        if (R1 < R2)      { ci = i1; Rw = R1; }
        else if (R2 < R1) { ci = i2; Rw = R2; }
        else              { ci = (i1 < i2) ? i1 : i2; Rw = R1; }

        if (!(Rw < (double)d2 - EGUARD)) {
            // full exact rescan (first-min => lowest index); rare
            double dmin = 1.0e300; int imin = 0;
#pragma unroll 1
            for (int c = 0; c < 256; ++c) {
                double R = rank64(cbw + (size_t)(cbase + c) * 64,
                                  cn64[cbase + c], rd);
                if (R < dmin) { dmin = R; imin = c; }
            }
            ci = imin;
        }

        // gather q, accumulate loss (fp64), f32 residual update (matches ref)
        const float* qp = cbf + (size_t)(cbase + ci) * 64;
        double lsse = 0.0;
#pragma unroll
        for (int q = 0; q < 16; ++q) {
            float4 qv = *reinterpret_cast<const float4*>(qp + q * 4);
            float r0 = rd[q * 4 + 0], r1 = rd[q * 4 + 1];
            float r2 = rd[q * 4 + 2], r3 = rd[q * 4 + 3];
            float e0 = qv.x - r0, e1 = qv.y - r1;
            float e2 = qv.z - r2, e3 = qv.w - r3;
            lsse = fma((double)e0, (double)e0, lsse);
            lsse = fma((double)e1, (double)e1, lsse);
            lsse = fma((double)e2, (double)e2, lsse);
            lsse = fma((double)e3, (double)e3, lsse);
            rd[q * 4 + 0] = r0 - qv.x; rd[q * 4 + 1] = r1 - qv.y;
            rd[q * 4 + 2] = r2 - qv.z; rd[q * 4 + 3] = r3 - qv.w;
        }
        sse += lsse;
        codes[(size_t)lv * Ntot + grow0 + lane] = (float)ci;
    }

    // ---- x_q = z - r_final ; per-block loss partial ----
    {
        size_t base = (size_t)(grow0 + lane) * 64;
#pragma unroll
        for (int q = 0; q < 16; ++q) {
            float4 zv = *reinterpret_cast<const float4*>(zr + q * 4);
            float4 o;
            o.x = zv.x - rd[q * 4 + 0];
            o.y = zv.y - rd[q * 4 + 1];
            o.z = zv.z - rd[q * 4 + 2];
            o.w = zv.w - rd[q * 4 + 3];
            *reinterpret_cast<float4*>(xq + base + q * 4) = o;
        }
        double s = sse;
#pragma unroll
        for (int off = 32; off > 0; off >>= 1) {
            union { double d; int i[2]; } u; u.d = s;
            u.i[0] = __shfl_down(u.i[0], off, 64);
            u.i[1] = __shfl_down(u.i[1], off, 64);
            s += u.d;
        }
        if (lane == 0) partials[grow0 >> 6] = s;
    }
}

// ---------------------------------------------------------------------------
__global__ void loss_final(const double* __restrict__ partials, int n,
                           float* __restrict__ out, double scale) {
    __shared__ double s[256];
    double acc = 0.0;
    for (int i = threadIdx.x; i < n; i += 256) acc += partials[i];
    s[threadIdx.x] = acc;
    __syncthreads();
    for (int off = 128; off > 0; off >>= 1) {
        if ((int)threadIdx.x < off) s[threadIdx.x] += s[threadIdx.x + off];
        __syncthreads();
    }
    if (threadIdx.x == 0) *out = (float)(s[0] * scale);
}

// ---------------------------------------------------------------------------
extern "C" void kernel_launch(void* const* d_in, const int* in_sizes, int n_in,
                              void* d_out, int out_size, void* d_ws, size_t ws_size,
                              hipStream_t stream) {
    const float* x  = (const float*)d_in[0];
    const float* W0 = (const float*)d_in[1];
    const float* b0 = (const float*)d_in[2];
    const float* W1 = (const float*)d_in[3];
    const float* b1 = (const float*)d_in[4];
    const float* W2 = (const float*)d_in[5];
    const float* b2 = (const float*)d_in[6];
    const float* cb = (const float*)d_in[7];

    const int N = in_sizes[0] / 768;

    float* out   = (float*)d_out;
    float* xq    = out;                      // [N*64]
    float* loss  = out + (size_t)N * 64;     // [1]
    float* codes = loss + 1;                 // [4*N]

    const int nblk_total = N / 64;
    const size_t tail_floats = 131072 + 2048 + 2 * (size_t)nblk_total + 1024 + 64;

    size_t avail = ws_size / 4;
    avail = (avail > tail_floats) ? (avail - tail_floats) : 0;
    int Nc = (int)(avail / 832);
    Nc = (Nc / 128) * 128;
    if (Nc > N) Nc = N;
    if (Nc < 128) Nc = 128;

    float* ws = (float*)d_ws;
    float* h0 = ws;
    float* h1 = h0 + (size_t)Nc * 512;
    float* z  = h1 + (size_t)Nc * 256;
    double* cbw      = (double*)(ws + (size_t)Nc * 832);  // 16B-aligned (Nc%128==0)
    double* cn64     = cbw + 65536;
    double* partials = cn64 + 1024;
    float*  cnf      = (float*)(partials + nblk_total);

    cb_norms <<<16, 64, 0, stream>>>(cb, cn64, cnf);
    build_cbw<<<256, 256, 0, stream>>>(cb, cbw);

    for (int r0 = 0; r0 < N; r0 += Nc) {
        int cur = (N - r0 < Nc) ? (N - r0) : Nc;
        gemm128<true, 2><<<dim3(512 / 128, cur / 128), 256, 0, stream>>>(
            x + (size_t)r0 * 768, W0, b0, h0, cur, 512, 768);
        gemm128<true, 1><<<dim3(256 / 128, cur / 128), 256, 0, stream>>>(
            h0, W1, b1, h1, cur, 256, 512);
        gemm_bias<false><<<dim3(1, cur / 128), 256, 0, stream>>>(
            h1, W2, b2, z, cur, 64, 256);
        rvq_w1<<<cur / 64, 64, 0, stream>>>(
            z, cb, cbw, cn64, cnf, xq, codes, partials, r0, N);
    }

    loss_final<<<1, 256, 0, stream>>>(partials, nblk_total, loss,
                                      1.25 / (4.0 * (double)N * 64.0));
}